// Round 12
// baseline (308.918 us; speedup 1.0000x reference)
//
#include <hip/hip_runtime.h>

#define H_ 448
#define CIN_ 128
#define HW_ (448*96)   // 43008
#define PPB 48

__device__ __forceinline__ float lrelu(float v){ return v > 0.0f ? v : 0.01f*v; }

// XCD-pairing decode: the two blocks of line h land on the same XCD (mod-8 round robin).
__device__ __forceinline__ void decode_block(int d, int& h, int& par){
    const int r = d & 15, q = d >> 4;
    h   = (r & 7) + (q << 3);
    par = r >> 3;
}

// Counting sort of 96 pixels by class (NC classes). All threads must call.
template<int NC>
__device__ __forceinline__ void sort96(const unsigned char* s_cls, short* s_perm,
                                       int* s_cnt, int* s_off, int t)
{
    if (t < NC){
        int c = 0;
        for (int p = 0; p < 96; p++) if (s_cls[p] == (unsigned char)t) c++;
        s_cnt[t] = c;
    }
    __syncthreads();
    if (t == 0){
        int a = 0;
        for (int c = 0; c < NC; c++){ s_off[c] = a; a += s_cnt[c]; }
    }
    __syncthreads();
    if (t < NC){
        int o = s_off[t];
        for (int p = 0; p < 96; p++) if (s_cls[p] == (unsigned char)t) s_perm[o++] = (short)p;
    }
    __syncthreads();
}

// ================= K1: stage 1 (half-line blocks) — R10 verbatim =================
__global__ __launch_bounds__(384, 4)
void k1_stage1(const float* __restrict__ X,
               const float* __restrict__ w1_0, const float* __restrict__ b1_0,
               const float* __restrict__ w1_1, const float* __restrict__ b1_1,
               const float* __restrict__ w1_2, const float* __restrict__ b1_2,
               unsigned char* __restrict__ inds1)
{
    __shared__ float s_w0[4096];
    __shared__ float s_w1[1024];
    __shared__ float s_w2[256];
    __shared__ float s_A[PPB*33];
    __shared__ float s_B[PPB*33];

    int h, par; decode_block(blockIdx.x, h, par);
    const int wb = par * PPB;
    const int t  = threadIdx.x;
    const int w  = t % PPB;
    const int s  = t / PPB;
    const int hw = h*96 + wb + w;

    const float* g0 = w1_0 + (size_t)h*4096;
    for (int j = t; j < 4096; j += 384) s_w0[j] = g0[j];
    const float* g1 = w1_1 + (size_t)h*1024;
    for (int j = t; j < 1024; j += 384) s_w1[j] = g1[j];
    const float* g2 = w1_2 + (size_t)h*256;
    for (int j = t; j < 256; j += 384) s_w2[j] = g2[j];
    __syncthreads();

    {
        float acc[4];
        const float* bp = b1_0 + h*32 + s*4;
        #pragma unroll
        for (int k=0;k<4;k++) acc[k] = bp[k];
        #pragma unroll 4
        for (int i4=0;i4<32;i4++){
            const float x0 = X[(size_t)(4*i4+0)*HW_ + hw];
            const float x1 = X[(size_t)(4*i4+1)*HW_ + hw];
            const float x2 = X[(size_t)(4*i4+2)*HW_ + hw];
            const float x3 = X[(size_t)(4*i4+3)*HW_ + hw];
            #pragma unroll
            for (int k=0;k<4;k++){
                const float4 q = *(const float4*)&s_w0[(s*4+k)*128 + 4*i4];
                acc[k] += x0*q.x; acc[k] += x1*q.y; acc[k] += x2*q.z; acc[k] += x3*q.w;
            }
        }
        #pragma unroll
        for (int k=0;k<4;k++) s_A[w*33 + s*4 + k] = lrelu(acc[k]);
    }
    __syncthreads();

    {
        float acc[4];
        const float* bp = b1_1 + h*32 + s*4;
        #pragma unroll
        for (int k=0;k<4;k++) acc[k] = bp[k];
        #pragma unroll
        for (int i4=0;i4<8;i4++){
            const float x0 = s_A[w*33 + 4*i4+0];
            const float x1 = s_A[w*33 + 4*i4+1];
            const float x2 = s_A[w*33 + 4*i4+2];
            const float x3 = s_A[w*33 + 4*i4+3];
            #pragma unroll
            for (int k=0;k<4;k++){
                const float4 q = *(const float4*)&s_w1[(s*4+k)*32 + 4*i4];
                acc[k] += x0*q.x; acc[k] += x1*q.y; acc[k] += x2*q.z; acc[k] += x3*q.w;
            }
        }
        #pragma unroll
        for (int k=0;k<4;k++) s_B[w*33 + s*4 + k] = lrelu(acc[k]);
    }
    __syncthreads();

    {
        float acc = b1_2[h*8 + s];
        #pragma unroll
        for (int i4=0;i4<8;i4++){
            const float4 q = *(const float4*)&s_w2[s*32 + 4*i4];
            acc += s_B[w*33 + 4*i4+0]*q.x;
            acc += s_B[w*33 + 4*i4+1]*q.y;
            acc += s_B[w*33 + 4*i4+2]*q.z;
            acc += s_B[w*33 + 4*i4+3]*q.w;
        }
        s_A[w*33 + s] = acc;
    }
    __syncthreads();

    if (s == 0){
        const float* sc = &s_A[w*33];
        float best = sc[0]; int bi = 0;
        #pragma unroll
        for (int k=1;k<8;k++){ const float v = sc[k]; if (v > best){ best = v; bi = k; } }
        inds1[hw] = (unsigned char)bi;
    }
}

// ================= K2/K3: wave-uniform-expert octet gather =================
// One wave processes up to 8 same-expert pixels (8 lanes each). Weight-load
// instructions are lane-uniform in the expert dim -> ONE 128B line per instr.
template<int NC, bool S3>
__global__ __launch_bounds__(384, 4)
void condmul_ebcast(const float* __restrict__ X,
                    const float* __restrict__ w0, const float* __restrict__ b0,
                    const float* __restrict__ w1, const float* __restrict__ b1,
                    const float* __restrict__ w2, const float* __restrict__ b2,
                    const unsigned char* __restrict__ route,
                    signed char* __restrict__ raw12,
                    unsigned char* __restrict__ cls2,
                    int* __restrict__ out)
{
    __shared__ unsigned char s_cls[96];
    __shared__ short s_perm[96];
    __shared__ int   s_cnt[NC];
    __shared__ int   s_off[NC];
    __shared__ int   s_chunk[96];     // (class<<16)|sorted_base, octets
    __shared__ int   s_nch;

    int h, par; decode_block(blockIdx.x, h, par);
    const int t = threadIdx.x;
    if (t < 96) s_cls[t] = route[h*96 + t];
    __syncthreads();
    sort96<NC>(s_cls, s_perm, s_cnt, s_off, t);
    if (t == 0){
        int n = 0;
        for (int c = 0; c < NC; c++)
            for (int b = 0; b < s_cnt[c]; b += 8)
                s_chunk[n++] = (c << 16) | (s_off[c] + b);
        s_nch = n;
    }
    __syncthreads();

    const int wv   = (t >> 6) + 6*par;   // global wave id across the line's 2 blocks: 0..11
    const int lane = t & 63;
    const int g    = lane >> 3;          // pixel slot 0..7 within chunk
    const int j    = lane & 7;           // owns channels 4j..4j+3 (L0/L1), {2j,2j+1} (L2)
    const int gb   = lane & ~7;
    const int nch  = s_nch;

    for (int ck = wv; ck < nch; ck += 12){
        const int info = s_chunk[ck];
        const int c    = info >> 16;
        const int base = info & 0xffff;
        const int m    = min(8, s_off[c] + s_cnt[c] - base);
        const int gi   = g < m ? g : m - 1;
        const int sp   = s_perm[base + gi];
        const long e   = (long)h*NC + c;
        const int hw   = h*96 + sp;

        // L0: 128 -> 32 (weight loads broadcast across all 8 groups)
        float4 acc = *(const float4*)&b0[e*32 + j*4];
        const float* W0 = w0 + e*4096 + j*4;
        #pragma unroll 8
        for (int i=0;i<128;i++){
            const float4 q = *(const float4*)&W0[i*32];
            const float xv = X[(size_t)i*HW_ + hw];
            acc.x += xv*q.x; acc.y += xv*q.y; acc.z += xv*q.z; acc.w += xv*q.w;
        }
        float a0[4] = { lrelu(acc.x), lrelu(acc.y), lrelu(acc.z), lrelu(acc.w) };

        // L1: 32 -> 32 (acts via in-group shfl; weights broadcast)
        float4 ac2 = *(const float4*)&b1[e*32 + j*4];
        const float* W1 = w1 + e*1024 + j*4;
        #pragma unroll
        for (int i=0;i<32;i++){
            const float xv = __shfl(a0[i&3], gb + (i>>2), 64);
            const float4 q = *(const float4*)&W1[i*32];
            ac2.x += xv*q.x; ac2.y += xv*q.y; ac2.z += xv*q.z; ac2.w += xv*q.w;
        }
        float a1[4] = { lrelu(ac2.x), lrelu(ac2.y), lrelu(ac2.z), lrelu(ac2.w) };

        // L2: 32 -> 16 (lane owns channels 2j, 2j+1)
        float2 sc = *(const float2*)&b2[e*16 + j*2];
        const float* W2 = w2 + e*512 + j*2;
        #pragma unroll
        for (int i=0;i<32;i++){
            const float xv = __shfl(a1[i&3], gb + (i>>2), 64);
            const float2 r = *(const float2*)&W2[i*16];
            sc.x += xv*r.x; sc.y += xv*r.y;
        }

        // per-pixel argmax over 16 channels via 8-lane butterfly (first-occurrence ties)
        float best = sc.x; int bi = j*2;
        if (sc.y > best){ best = sc.y; bi = j*2+1; }
        #pragma unroll
        for (int off=1; off<8; off<<=1){
            const float ob = __shfl_xor(best, off, 64);
            const int  obi = __shfl_xor(bi,  off, 64);
            if (ob > best || (ob == best && obi < bi)){ best = ob; bi = obi; }
        }
        if (j == 0 && g < m){
            if (S3){
                int v = (int)raw12[hw]*8 + bi - 4;
                v = v < 0 ? 0 : (v > 511 ? 511 : v);
                out[hw] = v;
            } else {
                const int raw = c*8 + bi - 4;   // c<8 -> raw in [-4,67], fits i8
                raw12[hw] = (signed char)raw;
                cls2[hw]  = (unsigned char)(raw < 0 ? 0 : (raw > 63 ? 63 : raw));
            }
        }
    }
}

extern "C" void kernel_launch(void* const* d_in, const int* in_sizes, int n_in,
                              void* d_out, int out_size, void* d_ws, size_t ws_size,
                              hipStream_t stream) {
    const float* X    = (const float*)d_in[0];
    const float* w1_0 = (const float*)d_in[1];
    const float* b1_0 = (const float*)d_in[2];
    const float* w1_1 = (const float*)d_in[3];
    const float* b1_1 = (const float*)d_in[4];
    const float* w1_2 = (const float*)d_in[5];
    const float* b1_2 = (const float*)d_in[6];
    const float* w2_0 = (const float*)d_in[7];
    const float* b2_0 = (const float*)d_in[8];
    const float* w2_1 = (const float*)d_in[9];
    const float* b2_1 = (const float*)d_in[10];
    const float* w2_2 = (const float*)d_in[11];
    const float* b2_2 = (const float*)d_in[12];
    const float* w3_0 = (const float*)d_in[13];
    const float* b3_0 = (const float*)d_in[14];
    const float* w3_1 = (const float*)d_in[15];
    const float* b3_1 = (const float*)d_in[16];
    const float* w3_2 = (const float*)d_in[17];
    const float* b3_2 = (const float*)d_in[18];
    int* out = (int*)d_out;

    unsigned char* inds1 = (unsigned char*)d_ws;
    unsigned char* cls2  = inds1 + HW_;
    signed char*   raw12 = (signed char*)(cls2 + HW_);

    k1_stage1<<<H_*2, 384, 0, stream>>>(X, w1_0, b1_0, w1_1, b1_1, w1_2, b1_2, inds1);
    condmul_ebcast<8,  false><<<H_*2, 384, 0, stream>>>(X, w2_0, b2_0, w2_1, b2_1, w2_2, b2_2,
                                                        inds1, raw12, cls2, out);
    condmul_ebcast<64, true ><<<H_*2, 384, 0, stream>>>(X, w3_0, b3_0, w3_1, b3_1, w3_2, b3_2,
                                                        cls2, raw12, cls2, out);
}